// Round 1
// baseline (9538.765 us; speedup 1.0000x reference)
//
#include <hip/hip_runtime.h>
#include <hip/hip_bf16.h>

// LSTM decoder: L=512, B=64, A=256, I=256, H=512, 4H=2048.
// Persistent kernel: 64 WGs, each owns 8 hidden units (32 gate rows).
// Weights live in registers as bf16 MFMA fragments; h broadcast via d_ws
// with per-step device-scope arrival counters.

#define NWG     64
#define LSTEPS  512
#define BATCH   64
#define HDIM    512
#define ADIM    256
#define GDIM    2048
#define KTOT    768
#define LBH     (LSTEPS*BATCH*HDIM)

typedef __attribute__((ext_vector_type(4))) float f32x4;
typedef __attribute__((ext_vector_type(8))) short s16x8;

__device__ __forceinline__ unsigned short f2bf(float f){
  unsigned u = __builtin_bit_cast(unsigned, f);
  u = (u + 0x7fffu + ((u >> 16) & 1u)) >> 16;   // round-to-nearest-even
  return (unsigned short)u;
}

// ---------------- precompute kernels ----------------

// action_features fp32 -> bf16 (same [L][B][A] layout), 8 elems/thread
__global__ void cvt_act(const float* __restrict__ in, unsigned short* __restrict__ ob, int n8){
  int i = blockIdx.x * blockDim.x + threadIdx.x;
  if (i >= n8) return;
  const float4* p = (const float4*)in + (size_t)i * 2;
  float4 a = p[0], b = p[1];
  int4 o;
  o.x = (int)((unsigned)f2bf(a.x) | ((unsigned)f2bf(a.y) << 16));
  o.y = (int)((unsigned)f2bf(a.z) | ((unsigned)f2bf(a.w) << 16));
  o.z = (int)((unsigned)f2bf(b.x) | ((unsigned)f2bf(b.y) << 16));
  o.w = (int)((unsigned)f2bf(b.z) | ((unsigned)f2bf(b.w) << 16));
  ((int4*)ob)[i] = o;
}

// static_gates[b][g] = input[b]·W_ih[g][0:256] + b_ih[g] + b_hh[g]   (fp32)
// grid = 2048 blocks (one gate row), 64 threads (one batch each)
__global__ void static_gates_k(const float* __restrict__ inp, const float* __restrict__ Wih,
                               const float* __restrict__ bih, const float* __restrict__ bhh,
                               float* __restrict__ statg){
  int g = blockIdx.x;
  int b = threadIdx.x;
  const float4* w = (const float4*)(Wih + (size_t)g * 512);  // first 256 cols = W_i
  const float4* x = (const float4*)(inp + (size_t)b * 256);
  float acc = 0.f;
#pragma unroll 8
  for (int i = 0; i < 64; ++i){
    float4 wv = w[i], xv = x[i];
    acc += wv.x*xv.x + wv.y*xv.y + wv.z*xv.z + wv.w*xv.w;
  }
  statg[b*GDIM + g] = acc + bih[g] + bhh[g];
}

// hbuf[1] <- bf16(h0)
__global__ void init_h(const float* __restrict__ h0, unsigned short* __restrict__ hbuf){
  int i = blockIdx.x * blockDim.x + threadIdx.x;
  if (i < BATCH*HDIM) hbuf[BATCH*HDIM + i] = f2bf(h0[i]);
}

// ---------------- persistent LSTM kernel ----------------

__global__ __launch_bounds__(256, 1) void lstm_persistent(
    const unsigned short* __restrict__ act_bf,   // [L][B][A] bf16
    const float*          __restrict__ statg,    // [B][4H]
    const float*          __restrict__ Whh,      // [4H][H]
    const float*          __restrict__ Wih,      // [4H][I+A]
    const float*          __restrict__ c0,       // [B][H]
    float*                __restrict__ out,      // hs [L][B][H], h_n, c_n
    unsigned short*       __restrict__ hbuf,     // [2][B][H] bf16
    unsigned int*         __restrict__ done)     // [L] arrival counters
{
  // A-tile: rows = batch (64), cols = K (768 = 512 h | 256 act), bf16, XOR-swizzled
  __shared__ short Albuf[64 * KTOT];
  __shared__ float gbuf[64 * 36];   // gate tile staging, padded stride 36

  const int tid  = threadIdx.x;
  const int wgk  = blockIdx.x;      // owns hidden units [8*wgk, 8*wgk+8)
  const int lane = tid & 63;
  const int wid  = tid >> 6;
  const int wm   = wid & 1;         // M (batch) half
  const int wn   = wid >> 1;        // N (col) half
  const int kgrp = (lane >> 4) * 8; // k sub-block within a K=32 MFMA step

  // ---- B fragments (weights) in registers, constant for all 512 steps ----
  const int cl   = wn*16 + (lane & 15);                    // local col 0..31
  const int grow = (cl >> 3)*512 + wgk*8 + (cl & 7);       // global gate row
  s16x8 bw[24];
#pragma unroll
  for (int kk = 0; kk < 16; ++kk){                          // K 0..511 : W_hh
    s16x8 v;
    const int kb = kk*32 + kgrp;
#pragma unroll
    for (int e = 0; e < 8; ++e)
      v[e] = (short)f2bf(Whh[(size_t)grow*512 + kb + e]);
    bw[kk] = v;
  }
#pragma unroll
  for (int kk = 16; kk < 24; ++kk){                         // K 512..767 : W_a
    s16x8 v;
    const int kb = kk*32 + kgrp;                            // 512..
#pragma unroll
    for (int e = 0; e < 8; ++e)
      v[e] = (short)f2bf(Wih[(size_t)grow*512 + (kb - 256) + e]); // col 256+(kb-512)
    bw[kk] = v;
  }

  // ---- per-thread cell state + static gates in registers ----
  float stat[2][4];
  float creg[2];
  int bidx[2], jidx[2], uidx[2];
#pragma unroll
  for (int pi = 0; pi < 2; ++pi){
    const int p = tid + pi*256;
    const int b = p >> 3, u = p & 7;
    const int j = wgk*8 + u;
    bidx[pi] = b; jidx[pi] = j; uidx[pi] = u;
#pragma unroll
    for (int g4 = 0; g4 < 4; ++g4)
      stat[pi][g4] = statg[b*GDIM + g4*512 + j];
    creg[pi] = c0[b*HDIM + j];
  }

  for (int t = 0; t < LSTEPS; ++t){
    // stage act part (independent of h -> before the barrier wait)
    {
      const unsigned short* asrc = act_bf + (size_t)t * (BATCH*ADIM);
#pragma unroll
      for (int it = 0; it < 8; ++it){
        const int idx = it*256 + tid;
        const int r = idx >> 5, ch = idx & 31;
        int4 v = *(const int4*)(asrc + r*ADIM + ch*8);
        *(int4*)(&Albuf[r*KTOT + 512 + ((ch ^ (r & 7)) * 8)]) = v;
      }
    }
    // wait until every WG published h_{t-1}
    if (t > 0){
      if (tid == 0){
        while (__hip_atomic_load(&done[t-1], __ATOMIC_ACQUIRE, __HIP_MEMORY_SCOPE_AGENT) < NWG){}
      }
      __syncthreads();
      __threadfence();
    }
    // stage h part
    {
      const unsigned short* hsrc = hbuf + ((t+1) & 1) * (BATCH*HDIM);
#pragma unroll
      for (int it = 0; it < 16; ++it){
        const int idx = it*256 + tid;
        const int r = idx >> 6, ch = idx & 63;
        int4 v = *(const int4*)(hsrc + r*HDIM + ch*8);
        *(int4*)(&Albuf[r*KTOT + ((ch ^ (r & 7)) * 8)]) = v;
      }
    }
    __syncthreads();

    // ---- MFMA: D[64 batch][32 cols] over K=768 ----
    f32x4 acc[2];
#pragma unroll
    for (int m = 0; m < 2; ++m){
      f32x4 a = {0.f, 0.f, 0.f, 0.f};
      const int r  = wm*32 + m*16 + (lane & 15);
      const short* arow = &Albuf[r * KTOT];
      const int sw = (r & 7) * 8;
#pragma unroll
      for (int kk = 0; kk < 24; ++kk){
        const int col = (kk*32 + kgrp) ^ sw;
        s16x8 af = *(const s16x8*)(arow + col);
        a = __builtin_amdgcn_mfma_f32_16x16x32_bf16(af, bw[kk], a, 0, 0, 0);
      }
      acc[m] = a;
    }
    // scatter gates to LDS (C/D layout: col=lane&15, row=(lane>>4)*4+reg)
#pragma unroll
    for (int m = 0; m < 2; ++m){
      const int base_b = wm*32 + m*16 + ((lane >> 4) * 4);
#pragma unroll
      for (int r4 = 0; r4 < 4; ++r4)
        gbuf[(base_b + r4)*36 + cl] = acc[m][r4];
    }
    __syncthreads();

    // ---- elementwise LSTM cell (each thread: 2 (batch,unit) pairs) ----
#pragma unroll
    for (int pi = 0; pi < 2; ++pi){
      const int b = bidx[pi], j = jidx[pi], u = uidx[pi];
      const float* gb = &gbuf[b*36];
      float iv = gb[u]      + stat[pi][0];
      float fv = gb[8 + u]  + stat[pi][1];
      float gv = gb[16 + u] + stat[pi][2];
      float ov = gb[24 + u] + stat[pi][3];
      iv = 1.f / (1.f + __expf(-iv));
      fv = 1.f / (1.f + __expf(-fv));
      gv = tanhf(gv);
      ov = 1.f / (1.f + __expf(-ov));
      float c = fv * creg[pi] + iv * gv;
      creg[pi] = c;
      float h = ov * tanhf(c);
      out[(size_t)(t*BATCH + b)*HDIM + j] = h;
      hbuf[(t & 1)*(BATCH*HDIM) + b*HDIM + j] = f2bf(h);
      if (t == LSTEPS-1){
        out[LBH + b*HDIM + j] = h;
        out[LBH + BATCH*HDIM + b*HDIM + j] = c;
      }
    }
    __threadfence();     // publish h slice (agent scope)
    __syncthreads();
    if (tid == 0)
      __hip_atomic_fetch_add(&done[t], 1u, __ATOMIC_RELEASE, __HIP_MEMORY_SCOPE_AGENT);
  }
}

// ---------------- launch ----------------

extern "C" void kernel_launch(void* const* d_in, const int* in_sizes, int n_in,
                              void* d_out, int out_size, void* d_ws, size_t ws_size,
                              hipStream_t stream){
  const float* act = (const float*)d_in[0];
  const float* inp = (const float*)d_in[1];
  const float* h0  = (const float*)d_in[2];
  const float* c0  = (const float*)d_in[3];
  const float* Wih = (const float*)d_in[4];
  const float* Whh = (const float*)d_in[5];
  const float* bih = (const float*)d_in[6];
  const float* bhh = (const float*)d_in[7];
  float* out = (float*)d_out;

  char* ws = (char*)d_ws;
  unsigned short* act_bf = (unsigned short*)ws;                          // 16 MiB
  unsigned short* hbuf   = (unsigned short*)(ws + 16777216);             // 128 KiB
  float*          statg  = (float*)(ws + 16777216 + 131072);             // 512 KiB
  unsigned int*   done   = (unsigned int*)(ws + 16777216 + 131072 + 524288);

  hipMemsetAsync(done, 0, LSTEPS * sizeof(unsigned int), stream);
  cvt_act<<<4096, 256, 0, stream>>>(act, act_bf, (LSTEPS*BATCH*ADIM)/8);
  static_gates_k<<<GDIM, 64, 0, stream>>>(inp, Wih, bih, bhh, statg);
  init_h<<<128, 256, 0, stream>>>(h0, hbuf);
  lstm_persistent<<<NWG, 256, 0, stream>>>(act_bf, statg, Whh, Wih, c0, out, hbuf, done);
}

// Round 2
// 2428.054 us; speedup vs baseline: 3.9286x; 3.9286x over previous
//
#include <hip/hip_runtime.h>
#include <hip/hip_bf16.h>

// LSTM decoder: L=512, B=64, A=256, I=256, H=512, 4H=2048.
// Persistent kernel: 64 WGs, each owns 8 hidden units (32 gate rows).
// Weights in registers as bf16 MFMA fragments.
// Cross-WG h exchange: cache-BYPASSING (sc1) relaxed atomics + one acquire
// fence per step -- never a per-poll buffer_inv, never a buffer_wbl2.

#define NWG     64
#define LSTEPS  512
#define BATCH   64
#define HDIM    512
#define ADIM    256
#define GDIM    2048
#define KTOT    768
#define LBH     (LSTEPS*BATCH*HDIM)

typedef __attribute__((ext_vector_type(4))) float f32x4;
typedef __attribute__((ext_vector_type(8))) short s16x8;

__device__ __forceinline__ unsigned short f2bf(float f){
  unsigned u = __builtin_bit_cast(unsigned, f);
  u = (u + 0x7fffu + ((u >> 16) & 1u)) >> 16;   // round-to-nearest-even
  return (unsigned short)u;
}
__device__ __forceinline__ float sigm(float x){ return 1.f / (1.f + __expf(-x)); }
__device__ __forceinline__ float ftanh(float x){ return 1.f - 2.f / (__expf(2.f*x) + 1.f); }

// ---------------- precompute kernels ----------------

__global__ void cvt_act(const float* __restrict__ in, unsigned short* __restrict__ ob, int n8){
  int i = blockIdx.x * blockDim.x + threadIdx.x;
  if (i >= n8) return;
  const float4* p = (const float4*)in + (size_t)i * 2;
  float4 a = p[0], b = p[1];
  int4 o;
  o.x = (int)((unsigned)f2bf(a.x) | ((unsigned)f2bf(a.y) << 16));
  o.y = (int)((unsigned)f2bf(a.z) | ((unsigned)f2bf(a.w) << 16));
  o.z = (int)((unsigned)f2bf(b.x) | ((unsigned)f2bf(b.y) << 16));
  o.w = (int)((unsigned)f2bf(b.z) | ((unsigned)f2bf(b.w) << 16));
  ((int4*)ob)[i] = o;
}

__global__ void static_gates_k(const float* __restrict__ inp, const float* __restrict__ Wih,
                               const float* __restrict__ bih, const float* __restrict__ bhh,
                               float* __restrict__ statg){
  int g = blockIdx.x;
  int b = threadIdx.x;
  const float4* w = (const float4*)(Wih + (size_t)g * 512);
  const float4* x = (const float4*)(inp + (size_t)b * 256);
  float acc = 0.f;
#pragma unroll 8
  for (int i = 0; i < 64; ++i){
    float4 wv = w[i], xv = x[i];
    acc += wv.x*xv.x + wv.y*xv.y + wv.z*xv.z + wv.w*xv.w;
  }
  statg[b*GDIM + g] = acc + bih[g] + bhh[g];
}

// hbuf32 buffer 1 <- bf16(h0) packed 2-per-u32
__global__ void init_h(const float* __restrict__ h0, unsigned int* __restrict__ hbuf32){
  int i = blockIdx.x * blockDim.x + threadIdx.x;
  if (i < BATCH*256){
    unsigned lo = f2bf(h0[2*i]), hi = f2bf(h0[2*i+1]);
    hbuf32[BATCH*256 + i] = lo | (hi << 16);
  }
}

// ---------------- persistent LSTM kernel ----------------

__global__ __launch_bounds__(256, 1) void lstm_persistent(
    const unsigned short* __restrict__ act_bf,   // [L][B][A] bf16
    const float*          __restrict__ statg,    // [B][4H]
    const float*          __restrict__ Whh,      // [4H][H]
    const float*          __restrict__ Wih,      // [4H][I+A]
    const float*          __restrict__ c0,       // [B][H]
    float*                __restrict__ out,      // hs [L][B][H], h_n, c_n
    unsigned int*         __restrict__ hbuf32,   // [2][B][H/2] packed bf16x2
    unsigned int*         __restrict__ done)     // [L] arrival counters
{
  __shared__ short Albuf[64 * KTOT];   // A-tile: 64 batch x 768 K, XOR-swizzled
  __shared__ float gbuf[64 * 36];      // gate staging, padded stride 36

  const int tid  = threadIdx.x;
  const int wgk  = blockIdx.x;         // owns hidden units [8*wgk, 8*wgk+8)
  const int lane = tid & 63;
  const int wid  = tid >> 6;
  const int wm   = wid & 1;
  const int wn   = wid >> 1;
  const int kgrp = (lane >> 4) * 8;

  // ---- B fragments (weights) in registers ----
  const int cl   = wn*16 + (lane & 15);                // local col 0..31
  const int grow = (cl >> 3)*512 + wgk*8 + (cl & 7);   // global gate row
  s16x8 bw[24];
#pragma unroll
  for (int kk = 0; kk < 16; ++kk){                     // K 0..511 : W_hh
    s16x8 v;
    const int kb = kk*32 + kgrp;
#pragma unroll
    for (int e = 0; e < 8; ++e)
      v[e] = (short)f2bf(Whh[(size_t)grow*512 + kb + e]);
    bw[kk] = v;
  }
#pragma unroll
  for (int kk = 16; kk < 24; ++kk){                    // K 512..767 : W_a
    s16x8 v;
    const int kb = kk*32 + kgrp;
#pragma unroll
    for (int e = 0; e < 8; ++e)
      v[e] = (short)f2bf(Wih[(size_t)grow*512 + (kb - 256) + e]);
    bw[kk] = v;
  }

  // ---- cell-update mapping: thread -> (batch b_cu, units j0, j0+1) ----
  const int b_cu = tid >> 2;           // 0..63
  const int u0   = (tid & 3) * 2;      // 0,2,4,6
  const int j0   = wgk*8 + u0;
  float stat2[2][4], cr[2];
#pragma unroll
  for (int pi = 0; pi < 2; ++pi){
    const int j = j0 + pi;
#pragma unroll
    for (int g4 = 0; g4 < 4; ++g4)
      stat2[pi][g4] = statg[b_cu*GDIM + g4*512 + j];
    cr[pi] = c0[b_cu*HDIM + j];
  }

  for (int t = 0; t < LSTEPS; ++t){
    // stage act part (independent of h -> before the wait)
    {
      const unsigned short* asrc = act_bf + (size_t)t * (BATCH*ADIM);
#pragma unroll
      for (int it = 0; it < 8; ++it){
        const int idx = it*256 + tid;
        const int r = idx >> 5, ch = idx & 31;
        int4 v = *(const int4*)(asrc + r*ADIM + ch*8);
        *(int4*)(&Albuf[r*KTOT + 512 + ((ch ^ (r & 7)) * 8)]) = v;
      }
    }
    // wait for h_{t-1}: relaxed poll (no cache invalidation per iteration),
    // then ONE acquire fence (single buffer_inv) before cached h reads.
    if (t > 0){
      while (__hip_atomic_load(&done[t-1], __ATOMIC_RELAXED, __HIP_MEMORY_SCOPE_AGENT) < NWG){}
      __builtin_amdgcn_fence(__ATOMIC_ACQUIRE, "agent");
    }
    // stage h part (regular pipelined 16B loads; caches were invalidated)
    {
      const int4* hp = (const int4*)(hbuf32 + ((t+1) & 1) * (BATCH*256));
#pragma unroll
      for (int it = 0; it < 16; ++it){
        const int idx = it*256 + tid;
        const int r = idx >> 6, ch = idx & 63;
        int4 v = hp[r*64 + ch];
        *(int4*)(&Albuf[r*KTOT + ((ch ^ (r & 7)) * 8)]) = v;
      }
    }
    __syncthreads();

    // ---- MFMA: D[64 batch][32 cols] over K=768 ----
    f32x4 acc[2];
#pragma unroll
    for (int m = 0; m < 2; ++m){
      f32x4 a = {0.f, 0.f, 0.f, 0.f};
      const int r  = wm*32 + m*16 + (lane & 15);
      const short* arow = &Albuf[r * KTOT];
      const int sw = (r & 7) * 8;
#pragma unroll
      for (int kk = 0; kk < 24; ++kk){
        const int col = (kk*32 + kgrp) ^ sw;
        s16x8 af = *(const s16x8*)(arow + col);
        a = __builtin_amdgcn_mfma_f32_16x16x32_bf16(af, bw[kk], a, 0, 0, 0);
      }
      acc[m] = a;
    }
    // scatter gates to LDS (C/D layout: col=lane&15, row=(lane>>4)*4+reg)
#pragma unroll
    for (int m = 0; m < 2; ++m){
      const int base_b = wm*32 + m*16 + ((lane >> 4) * 4);
#pragma unroll
      for (int r4 = 0; r4 < 4; ++r4)
        gbuf[(base_b + r4)*36 + cl] = acc[m][r4];
    }
    __syncthreads();

    // ---- elementwise LSTM cell: thread owns (b_cu, j0) and (b_cu, j0+1) ----
    {
      const float* gb = &gbuf[b_cu*36];
      float hv[2];
#pragma unroll
      for (int pi = 0; pi < 2; ++pi){
        const int u = u0 + pi;
        float iv = gb[u]      + stat2[pi][0];
        float fv = gb[8 + u]  + stat2[pi][1];
        float gv = gb[16 + u] + stat2[pi][2];
        float ov = gb[24 + u] + stat2[pi][3];
        iv = sigm(iv); fv = sigm(fv); gv = ftanh(gv); ov = sigm(ov);
        float c = fv * cr[pi] + iv * gv;
        cr[pi] = c;
        hv[pi] = ov * ftanh(c);
      }
      // hs output (8B coalesced-ish)
      float2 h2; h2.x = hv[0]; h2.y = hv[1];
      *(float2*)&out[((size_t)t*BATCH + b_cu)*HDIM + j0] = h2;
      // publish h: ONE cache-bypassing u32 store (sc1) -- no wbl2 needed
      unsigned pk = (unsigned)f2bf(hv[0]) | ((unsigned)f2bf(hv[1]) << 16);
      __hip_atomic_store(&hbuf32[(t & 1)*(BATCH*256) + b_cu*256 + (j0 >> 1)], pk,
                         __ATOMIC_RELAXED, __HIP_MEMORY_SCOPE_AGENT);
      if (t == LSTEPS-1){
        float2 c2; c2.x = cr[0]; c2.y = cr[1];
        *(float2*)&out[LBH + b_cu*HDIM + j0] = h2;
        *(float2*)&out[LBH + BATCH*HDIM + b_cu*HDIM + j0] = c2;
      }
    }
    // barrier drains vmcnt for all waves -> sc1 stores are at coherence point
    __syncthreads();
    if (tid == 0)
      __hip_atomic_fetch_add(&done[t], 1u, __ATOMIC_RELAXED, __HIP_MEMORY_SCOPE_AGENT);
  }
}

// ---------------- launch ----------------

extern "C" void kernel_launch(void* const* d_in, const int* in_sizes, int n_in,
                              void* d_out, int out_size, void* d_ws, size_t ws_size,
                              hipStream_t stream){
  const float* act = (const float*)d_in[0];
  const float* inp = (const float*)d_in[1];
  const float* h0  = (const float*)d_in[2];
  const float* c0  = (const float*)d_in[3];
  const float* Wih = (const float*)d_in[4];
  const float* Whh = (const float*)d_in[5];
  const float* bih = (const float*)d_in[6];
  const float* bhh = (const float*)d_in[7];
  float* out = (float*)d_out;

  char* ws = (char*)d_ws;
  unsigned short* act_bf = (unsigned short*)ws;                          // 16 MiB
  unsigned int*   hbuf32 = (unsigned int*)(ws + 16777216);               // 128 KiB
  float*          statg  = (float*)(ws + 16777216 + 131072);             // 512 KiB
  unsigned int*   done   = (unsigned int*)(ws + 16777216 + 131072 + 524288);

  hipMemsetAsync(done, 0, LSTEPS * sizeof(unsigned int), stream);
  cvt_act<<<4096, 256, 0, stream>>>(act, act_bf, (LSTEPS*BATCH*ADIM)/8);
  static_gates_k<<<GDIM, 64, 0, stream>>>(inp, Wih, bih, bhh, statg);
  init_h<<<64, 256, 0, stream>>>(h0, hbuf32);
  lstm_persistent<<<NWG, 256, 0, stream>>>(act_bf, statg, Whh, Wih, c0, out, hbuf32, done);
}